// Round 6
// baseline (395.638 us; speedup 1.0000x reference)
//
#include <hip/hip_runtime.h>
#include <hip/hip_bf16.h>

#define C 128
#define RBFD 20
#define NATOMS 50000
#define SCAN_CHUNK 1024
#define SLAB 256          // edges per gather block; 800000 % 256 == 0

// ---------------------------------------------------------------------------
// Kernel 1: setup — transpose W1, W2 into [in][out], zero histogram counters,
// zero the accumulator (needed: boundary atomics + atoms with zero edges).
// ---------------------------------------------------------------------------
__global__ __launch_bounds__(256) void setup_kernel(
    const float* __restrict__ W1, const float* __restrict__ W2,
    float* __restrict__ W1T, float* __restrict__ W2T,
    int* __restrict__ count, float4* __restrict__ acc4,
    int n, int acc_quads)
{
    const int t = blockIdx.x * blockDim.x + threadIdx.x;
    const int stride = gridDim.x * blockDim.x;
    if (t < C * C) {
        int k = t / C;   // in-channel
        int c = t % C;   // out-channel
        W1T[t] = W1[c * C + k];
        W2T[t] = W2[c * C + k];
    }
    for (int i = t; i < n; i += stride) count[i] = 0;
    const float4 z = make_float4(0.f, 0.f, 0.f, 0.f);
    for (int i = t; i < acc_quads; i += stride) acc4[i] = z;
}

// ---------------------------------------------------------------------------
// CSR construction: histogram -> hierarchical exclusive scan -> perm fill
// ---------------------------------------------------------------------------
__global__ __launch_bounds__(256) void histogram_kernel(
    const int* __restrict__ idx, int* __restrict__ count, int E)
{
    int e = blockIdx.x * blockDim.x + threadIdx.x;
    if (e < E) atomicAdd(&count[idx[e]], 1);
}

__global__ __launch_bounds__(256) void scan_partials_kernel(
    const int* __restrict__ count, int* __restrict__ partial, int n)
{
    __shared__ int sm[256];
    const int start = blockIdx.x * SCAN_CHUNK;
    int s = 0;
    for (int i = threadIdx.x; i < SCAN_CHUNK; i += 256) {
        int g = start + i;
        if (g < n) s += count[g];
    }
    sm[threadIdx.x] = s;
    __syncthreads();
    for (int off = 128; off > 0; off >>= 1) {
        if (threadIdx.x < off) sm[threadIdx.x] += sm[threadIdx.x + off];
        __syncthreads();
    }
    if (threadIdx.x == 0) partial[blockIdx.x] = sm[0];
}

__global__ void scan_chunkbase_kernel(int* __restrict__ partial,
                                      int* __restrict__ base,
                                      int nchunks, int n)
{
    if (threadIdx.x == 0 && blockIdx.x == 0) {
        int run = 0;
        for (int k = 0; k < nchunks; ++k) {
            int t = partial[k];
            partial[k] = run;
            run += t;
        }
        base[n] = run;
    }
}

__global__ __launch_bounds__(1024) void scan_apply_kernel(
    const int* __restrict__ count, const int* __restrict__ chunk_base,
    int* __restrict__ base, int* __restrict__ cursor, int n)
{
    __shared__ int sm[SCAN_CHUNK];
    const int t = threadIdx.x;
    const int i = blockIdx.x * SCAN_CHUNK + t;
    int v = (i < n) ? count[i] : 0;
    sm[t] = v;
    __syncthreads();
    for (int off = 1; off < SCAN_CHUNK; off <<= 1) {
        int tmp = (t >= off) ? sm[t - off] : 0;
        __syncthreads();
        sm[t] += tmp;
        __syncthreads();
    }
    if (i < n) {
        int excl = sm[t] - v + chunk_base[blockIdx.x];
        base[i] = excl;
        cursor[i] = excl;
    }
}

// also records the owner atom of each perm slot (sequential-read later)
__global__ __launch_bounds__(256) void fill_perm_kernel(
    const int* __restrict__ idx, int* __restrict__ cursor,
    int* __restrict__ perm, int* __restrict__ own, int E)
{
    int e = blockIdx.x * blockDim.x + threadIdx.x;
    if (e < E) {
        int a = idx[e];
        int pos = atomicAdd(&cursor[a], 1);
        perm[pos] = e;
        own[pos] = a;
    }
}

// ---------------------------------------------------------------------------
// Gather kernel v4: slab-parallel segmented reduction.
// One 128-thread block per 256-edge slab of the CSR-sorted perm array.
// Owners are non-decreasing within a slab -> register accumulation with
// flush-on-owner-change; plain store for slab-interior atoms, atomicAdd only
// for the slab's first/last owner.
// ---------------------------------------------------------------------------
__global__ __launch_bounds__(128) void gather_kernel(
    const float* __restrict__ x,       // [E][C]
    const float* __restrict__ rbf,     // [E][RBFD]
    const float* __restrict__ env,     // [E]
    const int*   __restrict__ perm,    // [E]
    const int*   __restrict__ own,     // [E]
    const float* __restrict__ Wrbf,    // [C][RBFD]
    const float* __restrict__ brbf,    // [C]
    float* __restrict__ acc)           // [N][C] (pre-zeroed)
{
    __shared__ int   e_s[SLAB];
    __shared__ float env_s[SLAB];
    __shared__ int   own_s[SLAB];

    const int tid = threadIdx.x;      // 0..127, = channel
    const int p0  = blockIdx.x * SLAB;

    // stage slab metadata: perm/own sequential, env gathered (4B each)
    for (int i = tid; i < SLAB; i += 128) {
        const int e = perm[p0 + i];
        e_s[i]   = e;
        env_s[i] = env[e];
        own_s[i] = own[p0 + i];
    }

    float w[RBFD];
#pragma unroll
    for (int r = 0; r < RBFD; ++r) w[r] = Wrbf[tid * RBFD + r];
    const float bias = brbf[tid];

    __syncthreads();

    const int first_own = own_s[0];
    const int last_own  = own_s[SLAB - 1];

    int   cur = first_own;
    float sum = 0.0f;

    for (int g = 0; g < SLAB; g += 4) {
        const int e0 = e_s[g + 0], e1 = e_s[g + 1];
        const int e2 = e_s[g + 2], e3 = e_s[g + 3];
        const float m0 = env_s[g + 0], m1 = env_s[g + 1];
        const float m2 = env_s[g + 2], m3 = env_s[g + 3];
        const int o0 = own_s[g + 0], o1 = own_s[g + 1];
        const int o2 = own_s[g + 2], o3 = own_s[g + 3];

        // ---- load phase: all global loads issued before any consumption ----
        const float4* r40 = reinterpret_cast<const float4*>(rbf + (size_t)e0 * RBFD);
        const float4* r41 = reinterpret_cast<const float4*>(rbf + (size_t)e1 * RBFD);
        const float4* r42 = reinterpret_cast<const float4*>(rbf + (size_t)e2 * RBFD);
        const float4* r43 = reinterpret_cast<const float4*>(rbf + (size_t)e3 * RBFD);
        float4 A0 = r40[0], A1 = r40[1], A2 = r40[2], A3 = r40[3], A4 = r40[4];
        float4 B0 = r41[0], B1 = r41[1], B2 = r41[2], B3 = r41[3], B4 = r41[4];
        float4 D0 = r42[0], D1 = r42[1], D2 = r42[2], D3 = r42[3], D4 = r42[4];
        float4 E0 = r43[0], E1 = r43[1], E2 = r43[2], E3 = r43[3], E4 = r43[4];
        const float x0 = x[(size_t)e0 * C + tid];
        const float x1 = x[(size_t)e1 * C + tid];
        const float x2 = x[(size_t)e2 * C + tid];
        const float x3 = x[(size_t)e3 * C + tid];

        // ---- compute phase ----
        float f0 = bias, f1 = bias, f2 = bias, f3 = bias;
        f0 = fmaf(A0.x,w[0],f0); f0 = fmaf(A0.y,w[1],f0); f0 = fmaf(A0.z,w[2],f0); f0 = fmaf(A0.w,w[3],f0);
        f0 = fmaf(A1.x,w[4],f0); f0 = fmaf(A1.y,w[5],f0); f0 = fmaf(A1.z,w[6],f0); f0 = fmaf(A1.w,w[7],f0);
        f0 = fmaf(A2.x,w[8],f0); f0 = fmaf(A2.y,w[9],f0); f0 = fmaf(A2.z,w[10],f0); f0 = fmaf(A2.w,w[11],f0);
        f0 = fmaf(A3.x,w[12],f0); f0 = fmaf(A3.y,w[13],f0); f0 = fmaf(A3.z,w[14],f0); f0 = fmaf(A3.w,w[15],f0);
        f0 = fmaf(A4.x,w[16],f0); f0 = fmaf(A4.y,w[17],f0); f0 = fmaf(A4.z,w[18],f0); f0 = fmaf(A4.w,w[19],f0);

        f1 = fmaf(B0.x,w[0],f1); f1 = fmaf(B0.y,w[1],f1); f1 = fmaf(B0.z,w[2],f1); f1 = fmaf(B0.w,w[3],f1);
        f1 = fmaf(B1.x,w[4],f1); f1 = fmaf(B1.y,w[5],f1); f1 = fmaf(B1.z,w[6],f1); f1 = fmaf(B1.w,w[7],f1);
        f1 = fmaf(B2.x,w[8],f1); f1 = fmaf(B2.y,w[9],f1); f1 = fmaf(B2.z,w[10],f1); f1 = fmaf(B2.w,w[11],f1);
        f1 = fmaf(B3.x,w[12],f1); f1 = fmaf(B3.y,w[13],f1); f1 = fmaf(B3.z,w[14],f1); f1 = fmaf(B3.w,w[15],f1);
        f1 = fmaf(B4.x,w[16],f1); f1 = fmaf(B4.y,w[17],f1); f1 = fmaf(B4.z,w[18],f1); f1 = fmaf(B4.w,w[19],f1);

        f2 = fmaf(D0.x,w[0],f2); f2 = fmaf(D0.y,w[1],f2); f2 = fmaf(D0.z,w[2],f2); f2 = fmaf(D0.w,w[3],f2);
        f2 = fmaf(D1.x,w[4],f2); f2 = fmaf(D1.y,w[5],f2); f2 = fmaf(D1.z,w[6],f2); f2 = fmaf(D1.w,w[7],f2);
        f2 = fmaf(D2.x,w[8],f2); f2 = fmaf(D2.y,w[9],f2); f2 = fmaf(D2.z,w[10],f2); f2 = fmaf(D2.w,w[11],f2);
        f2 = fmaf(D3.x,w[12],f2); f2 = fmaf(D3.y,w[13],f2); f2 = fmaf(D3.z,w[14],f2); f2 = fmaf(D3.w,w[15],f2);
        f2 = fmaf(D4.x,w[16],f2); f2 = fmaf(D4.y,w[17],f2); f2 = fmaf(D4.z,w[18],f2); f2 = fmaf(D4.w,w[19],f2);

        f3 = fmaf(E0.x,w[0],f3); f3 = fmaf(E0.y,w[1],f3); f3 = fmaf(E0.z,w[2],f3); f3 = fmaf(E0.w,w[3],f3);
        f3 = fmaf(E1.x,w[4],f3); f3 = fmaf(E1.y,w[5],f3); f3 = fmaf(E1.z,w[6],f3); f3 = fmaf(E1.w,w[7],f3);
        f3 = fmaf(E2.x,w[8],f3); f3 = fmaf(E2.y,w[9],f3); f3 = fmaf(E2.z,w[10],f3); f3 = fmaf(E2.w,w[11],f3);
        f3 = fmaf(E3.x,w[12],f3); f3 = fmaf(E3.y,w[13],f3); f3 = fmaf(E3.z,w[14],f3); f3 = fmaf(E3.w,w[15],f3);
        f3 = fmaf(E4.x,w[16],f3); f3 = fmaf(E4.y,w[17],f3); f3 = fmaf(E4.z,w[18],f3); f3 = fmaf(E4.w,w[19],f3);

        const float v0 = f0 * m0 * x0;
        const float v1 = f1 * m1 * x1;
        const float v2 = f2 * m2 * x2;
        const float v3 = f3 * m3 * x3;

        // ---- segmented accumulate (owner checks are wave-uniform) ----
        if (o0 != cur) {
            if (cur == first_own) unsafeAtomicAdd(&acc[(size_t)cur * C + tid], sum);
            else                  acc[(size_t)cur * C + tid] = sum;
            sum = 0.0f; cur = o0;
        }
        sum += v0;
        if (o1 != cur) {
            if (cur == first_own) unsafeAtomicAdd(&acc[(size_t)cur * C + tid], sum);
            else                  acc[(size_t)cur * C + tid] = sum;
            sum = 0.0f; cur = o1;
        }
        sum += v1;
        if (o2 != cur) {
            if (cur == first_own) unsafeAtomicAdd(&acc[(size_t)cur * C + tid], sum);
            else                  acc[(size_t)cur * C + tid] = sum;
            sum = 0.0f; cur = o2;
        }
        sum += v2;
        if (o3 != cur) {
            if (cur == first_own) unsafeAtomicAdd(&acc[(size_t)cur * C + tid], sum);
            else                  acc[(size_t)cur * C + tid] = sum;
            sum = 0.0f; cur = o3;
        }
        sum += v3;
    }
    // final flush: cur == last_own (may span into next slab) -> atomic
    unsafeAtomicAdd(&acc[(size_t)cur * C + tid], sum);
}

// ---------------------------------------------------------------------------
// Fused MLP head (unchanged).
// ---------------------------------------------------------------------------
__device__ __forceinline__ float silu_f(float v) {
    return v * (1.0f / (1.0f + __expf(-v)));
}

__global__ __launch_bounds__(256) void mlp_head_kernel(
    const float* __restrict__ acc,   // [N][C]
    const float* __restrict__ W1T,   // [C][C]  (k-major)
    const float* __restrict__ b1,    // [C]
    const float* __restrict__ W2T,   // [C][C]
    const float* __restrict__ b2,    // [C]
    const float* __restrict__ W3,    // [1][C]
    const float* __restrict__ b3,    // [1]
    float* __restrict__ out,         // [N]
    int natoms)
{
    __shared__ float As[C][C + 1];

    const int tid = threadIdx.x;
    const int a0  = blockIdx.x * C;
    const int tc  = tid & 15;
    const int ta  = tid >> 4;
    const int abase = ta * 8;
    const int cbase = tc * 8;

    {
        const int sub = tid >> 7;
        const int k   = tid & 127;
        for (int pair = 0; pair < 64; ++pair) {
            const int al = pair * 2 + sub;
            const int a  = a0 + al;
            float v = (a < natoms) ? acc[(size_t)a * C + k] : 0.0f;
            As[k][al] = v;
        }
    }
    __syncthreads();

    float r[8][8];

    // layer 1
#pragma unroll
    for (int i = 0; i < 8; ++i)
#pragma unroll
        for (int j = 0; j < 8; ++j) r[i][j] = 0.0f;

#pragma unroll 2
    for (int k = 0; k < C; ++k) {
        float4 bq0 = *reinterpret_cast<const float4*>(W1T + k * C + cbase);
        float4 bq1 = *reinterpret_cast<const float4*>(W1T + k * C + cbase + 4);
        float bv[8] = {bq0.x, bq0.y, bq0.z, bq0.w, bq1.x, bq1.y, bq1.z, bq1.w};
        float av[8];
#pragma unroll
        for (int i = 0; i < 8; ++i) av[i] = As[k][abase + i];
#pragma unroll
        for (int i = 0; i < 8; ++i)
#pragma unroll
            for (int j = 0; j < 8; ++j) r[i][j] = fmaf(av[i], bv[j], r[i][j]);
    }

    __syncthreads();
    {
        float bb[8];
#pragma unroll
        for (int j = 0; j < 8; ++j) bb[j] = b1[cbase + j];
#pragma unroll
        for (int i = 0; i < 8; ++i)
#pragma unroll
            for (int j = 0; j < 8; ++j)
                As[cbase + j][abase + i] = silu_f(r[i][j] + bb[j]);
    }
    __syncthreads();

    // layer 2
#pragma unroll
    for (int i = 0; i < 8; ++i)
#pragma unroll
        for (int j = 0; j < 8; ++j) r[i][j] = 0.0f;

#pragma unroll 2
    for (int k = 0; k < C; ++k) {
        float4 bq0 = *reinterpret_cast<const float4*>(W2T + k * C + cbase);
        float4 bq1 = *reinterpret_cast<const float4*>(W2T + k * C + cbase + 4);
        float bv[8] = {bq0.x, bq0.y, bq0.z, bq0.w, bq1.x, bq1.y, bq1.z, bq1.w};
        float av[8];
#pragma unroll
        for (int i = 0; i < 8; ++i) av[i] = As[k][abase + i];
#pragma unroll
        for (int i = 0; i < 8; ++i)
#pragma unroll
            for (int j = 0; j < 8; ++j) r[i][j] = fmaf(av[i], bv[j], r[i][j]);
    }

    __syncthreads();

    // final: silu(.. + b2) . W3
    {
        float bb[8], w3v[8];
#pragma unroll
        for (int j = 0; j < 8; ++j) bb[j] = b2[cbase + j];
        float4 wq0 = *reinterpret_cast<const float4*>(W3 + cbase);
        float4 wq1 = *reinterpret_cast<const float4*>(W3 + cbase + 4);
        w3v[0]=wq0.x; w3v[1]=wq0.y; w3v[2]=wq0.z; w3v[3]=wq0.w;
        w3v[4]=wq1.x; w3v[5]=wq1.y; w3v[6]=wq1.z; w3v[7]=wq1.w;

#pragma unroll
        for (int i = 0; i < 8; ++i) {
            float p = 0.0f;
#pragma unroll
            for (int j = 0; j < 8; ++j)
                p = fmaf(silu_f(r[i][j] + bb[j]), w3v[j], p);
            As[abase + i][tc] = p;
        }
    }
    __syncthreads();

    if (tid < C) {
        const int a = a0 + tid;
        if (a < natoms) {
            float s = 0.0f;
#pragma unroll
            for (int t = 0; t < 16; ++t) s += As[tid][t];
            out[a] = s + b3[0];
        }
    }
}

// ---------------------------------------------------------------------------
extern "C" void kernel_launch(void* const* d_in, const int* in_sizes, int n_in,
                              void* d_out, int out_size, void* d_ws, size_t ws_size,
                              hipStream_t stream) {
    const float* x      = (const float*)d_in[0];
    const float* rbf    = (const float*)d_in[1];
    const float* env    = (const float*)d_in[2];
    const int*   idx    = (const int*)  d_in[3];
    const float* Wrbf   = (const float*)d_in[5];
    const float* brbf   = (const float*)d_in[6];
    const float* W1     = (const float*)d_in[7];
    const float* b1     = (const float*)d_in[8];
    const float* W2     = (const float*)d_in[9];
    const float* b2     = (const float*)d_in[10];
    const float* W3     = (const float*)d_in[11];
    const float* b3     = (const float*)d_in[12];
    float*       out    = (float*)d_out;

    const int E = in_sizes[0] / C;        // 800000
    const int N = NATOMS;                 // 50000
    const int nchunks = (N + SCAN_CHUNK - 1) / SCAN_CHUNK;   // 49

    // workspace layout
    float* acc     = (float*)d_ws;                    // N*C
    float* W1T     = acc + (size_t)N * C;             // C*C
    float* W2T     = W1T + C * C;                     // C*C
    int*   count   = (int*)(W2T + C * C);             // N
    int*   base    = count + N;                       // N+1
    int*   cursor  = base + (N + 1);                  // N
    int*   partial = cursor + N;                      // 64
    int*   perm    = partial + 64;                    // E
    int*   own     = perm + E;                        // E

    // setup: transpose weights + zero counters + zero acc
    setup_kernel<<<2048, 256, 0, stream>>>(W1, W2, W1T, W2T, count,
                                           (float4*)acc, N, (N * C) / 4);

    histogram_kernel<<<(E + 255) / 256, 256, 0, stream>>>(idx, count, E);
    scan_partials_kernel<<<nchunks, 256, 0, stream>>>(count, partial, N);
    scan_chunkbase_kernel<<<1, 64, 0, stream>>>(partial, base, nchunks, N);
    scan_apply_kernel<<<nchunks, SCAN_CHUNK, 0, stream>>>(count, partial, base, cursor, N);
    fill_perm_kernel<<<(E + 255) / 256, 256, 0, stream>>>(idx, cursor, perm, own, E);

    // gather: one 128-thread block per 256-edge slab
    gather_kernel<<<E / SLAB, 128, 0, stream>>>(x, rbf, env, perm, own,
                                                Wrbf, brbf, acc);

    const int tiles = (N + C - 1) / C;
    mlp_head_kernel<<<tiles, 256, 0, stream>>>(acc, W1T, b1, W2T, b2, W3, b3, out, N);
}